// Round 10
// baseline (1154.800 us; speedup 1.0000x reference)
//
#include <hip/hip_runtime.h>
#include <stdint.h>

typedef short bfrag __attribute__((ext_vector_type(8)));   // 8 bf16 (4 VGPR)
typedef float facc4 __attribute__((ext_vector_type(4)));   // MFMA accumulator

__device__ __forceinline__ unsigned short f2bf(float x){
  union { float f; uint32_t u; } v; v.f = x;
  uint32_t r = v.u + 0x7FFFu + ((v.u >> 16) & 1u);   // RNE
  return (unsigned short)(r >> 16);
}
__device__ __forceinline__ float bf2f(unsigned short h){
  union { uint32_t u; float f; } v; v.u = ((uint32_t)h) << 16; return v.f;
}
__device__ __forceinline__ uint32_t pack2(unsigned short a, unsigned short b){
  return (uint32_t)a | ((uint32_t)b << 16);
}

__device__ __forceinline__ void gload_lds16(const void* g, void* l){
  __builtin_amdgcn_global_load_lds(
      (const __attribute__((address_space(1))) void*)g,
      (__attribute__((address_space(3))) void*)l, 16, 0, 0);
}

// ---------------------------------------------------------------------------
// 256x256 bf16 GEMM, 8 waves (2M x 4N), BK=64, 128 KB LDS dbuf, 1 block/CU.
//
// LDS fragment-major (0 conflicts, verified r6-r9): frag f = rg*2+ks, 1KB,
// exact MFMA lane order; DMA write and ds_read_b128 both contiguous 1KB.
//
// r10 schedule: 2 barriers/tile, LDS reads overlapped with MFMA.
//   tile t: [barrier from t-1 end: buf cur fully staged]
//     issue ALL 8 gloads for t+1 -> buf^1   (issue-early; buf^1 dead since
//                                            the t-1 end barrier)
//     read B(8 b128) + A phase0 (4)
//     p0: read A p1 (4) ; 16 MFMA (p0 frags)   <- reads fly under MFMAs
//     p1: read A p2 (4) ; 16 MFMA
//     p2: read A p3 (4) ; 16 MFMA
//     p3:                16 MFMA
//     vmcnt(0)   [t+1's 8 loads issued ~3000 cyc ago -> near-free drain]
//     barrier    [all reads of cur retired before their consuming MFMAs]
// Rationale: r7-r9's per-phase barrier lockstep serialized the LDS pipe
// (~2300 cyc/tile) against the MFMA pipe (~2480 cyc/tile) -> 5660 cyc/tile
// observed. Overlapping them targets ~3300 cyc/tile.
//
// REMAP=1: A,B are [hi|lo], NT=48 encodes Ah*Bh+Ah*Bl+Al*Bh via
// akt=(kt<16?kt:kt-16), bkt=(kt<32?kt:kt-32). REMAP=0: plain, NT=K/64.
// OUT: 0 = f32 C. 1 = split write hi at [row*2048+col], lo at +1024.
// T1: bijective XCD swizzle (m204) on flattened block id.
// ---------------------------------------------------------------------------
template<int REMAP, int OUT>
__global__ __launch_bounds__(512, 1)
void gemm256(const unsigned short* __restrict__ A,
             const unsigned short* __restrict__ B,
             void* __restrict__ C,
             int NT, int lda, int ldb, int ldc,
             long abstr, long bbstr, long cbstr)
{
  __shared__ __align__(16) unsigned short lds[2][2][16384];   // 128 KB

  const int tid  = threadIdx.x;
  const int lane = tid & 63;
  const int wv   = tid >> 6;          // 0..7
  const int wm   = wv >> 2;           // 0..1  -> 128 rows
  const int wn   = wv & 3;            // 0..3  -> 64 cols

  // T1: bijective XCD-aware remap of the flattened block id (m204)
  const int gx = gridDim.x, gy = gridDim.y;
  const int nwg  = gx * gy * (int)gridDim.z;
  const int orig = blockIdx.x + gx * (blockIdx.y + gy * blockIdx.z);
  const int qd = nwg >> 3, rm = nwg & 7;
  const int xcd = orig & 7, idx = orig >> 3;
  const int swz = (xcd < rm ? xcd * (qd + 1) : rm * (qd + 1) + (xcd - rm) * qd) + idx;
  const int m0 = (swz % gx) * 256;
  const int rest = swz / gx;
  const int n0 = (rest % gy) * 256;
  const int z  = rest / gy;

  const unsigned short* Ab = A + (size_t)z * (size_t)abstr;
  const unsigned short* Bb = B + (size_t)z * (size_t)bbstr;

  const int fr  = lane & 15;
  const int fkc = lane >> 4;          // 0..3

  // stage one A-frag of group G_p (8 frags, one per wave)
  auto stageA1 = [&](int buf, int kt, int p){
    int akt = kt; if (REMAP) akt = (kt < 16) ? kt : kt - 16;
    const int rg = 2 * p + (wv & 1) + ((wv & 4) << 1);
    const int ks = (wv >> 1) & 1;
    const int f  = rg * 2 + ks;
    gload_lds16(Ab + (size_t)(m0 + rg * 16 + fr) * lda + akt * 64 + ks * 32 + fkc * 8,
                &lds[buf][0][f * 512]);
  };
  // stage one quarter of B (8 frags, one per wave); j = 0..3 covers all 32
  auto stageB = [&](int buf, int kt, int j){
    int bkt = kt; if (REMAP) bkt = (kt < 32) ? kt : kt - 32;
    const int f = j * 8 + wv, rg = f >> 1, ks = f & 1;
    gload_lds16(Bb + (size_t)(n0 + rg * 16 + fr) * ldb + bkt * 64 + ks * 32 + fkc * 8,
                &lds[buf][1][f * 512]);
  };
  auto stageTile = [&](int buf, int kt){
    #pragma unroll
    for (int j = 0; j < 4; ++j) stageB(buf, kt, j);
    #pragma unroll
    for (int p = 0; p < 4; ++p) stageA1(buf, kt, p);
  };

  facc4 acc[8][4];
  #pragma unroll
  for (int a = 0; a < 8; ++a)
    #pragma unroll
    for (int b = 0; b < 4; ++b)
      acc[a][b] = (facc4){0.f, 0.f, 0.f, 0.f};

  // prologue: stage tile 0 fully, drain, barrier
  stageTile(0, 0);
  asm volatile("s_waitcnt vmcnt(0)" ::: "memory");
  asm volatile("s_barrier" ::: "memory");

  for (int t = 0; t < NT; ++t){
    const int cur = t & 1;
    const unsigned short* la = lds[cur][0];
    const unsigned short* lb = lds[cur][1];

    // issue next tile's staging first (issue-early / drain-late)
    if (t + 1 < NT) stageTile(cur ^ 1, t + 1);

    // A-frag read helper: frag (mi, ks) of this wave's row block
    #define RDA(mi, ks) (*(const bfrag*)(la + (((wm * 8 + (mi)) * 2 + (ks)) << 9) + lane * 8))

    // read all B fragments once per tile
    bfrag bv[4][2];
    #pragma unroll
    for (int ni = 0; ni < 4; ++ni){
      bv[ni][0] = *(const bfrag*)(lb + ((((wn * 4 + ni) * 2) + 0) << 9) + lane * 8);
      bv[ni][1] = *(const bfrag*)(lb + ((((wn * 4 + ni) * 2) + 1) << 9) + lane * 8);
    }

    // phase-0 A frags
    bfrag ax0 = RDA(0,0), ax1 = RDA(0,1), ax2 = RDA(1,0), ax3 = RDA(1,1);
    bfrag ay0, ay1, ay2, ay3;

    // 16-MFMA cluster: acc rows MI,MI+1; ks-major (independent first)
    #define MFMA16(MI, f0, f1, f2, f3)                                        \
      __builtin_amdgcn_s_setprio(1);                                          \
      _Pragma("unroll")                                                       \
      for (int ni = 0; ni < 4; ++ni){                                         \
        acc[MI][ni]   = __builtin_amdgcn_mfma_f32_16x16x32_bf16(f0, bv[ni][0], acc[MI][ni],   0, 0, 0); \
        acc[MI+1][ni] = __builtin_amdgcn_mfma_f32_16x16x32_bf16(f2, bv[ni][0], acc[MI+1][ni], 0, 0, 0); \
      }                                                                       \
      _Pragma("unroll")                                                       \
      for (int ni = 0; ni < 4; ++ni){                                         \
        acc[MI][ni]   = __builtin_amdgcn_mfma_f32_16x16x32_bf16(f1, bv[ni][1], acc[MI][ni],   0, 0, 0); \
        acc[MI+1][ni] = __builtin_amdgcn_mfma_f32_16x16x32_bf16(f3, bv[ni][1], acc[MI+1][ni], 0, 0, 0); \
      }                                                                       \
      __builtin_amdgcn_s_setprio(0);

    // p0: prefetch p1 frags, compute mi 0-1
    ay0 = RDA(2,0); ay1 = RDA(2,1); ay2 = RDA(3,0); ay3 = RDA(3,1);
    MFMA16(0, ax0, ax1, ax2, ax3)
    // p1: prefetch p2 frags, compute mi 2-3
    ax0 = RDA(4,0); ax1 = RDA(4,1); ax2 = RDA(5,0); ax3 = RDA(5,1);
    MFMA16(2, ay0, ay1, ay2, ay3)
    // p2: prefetch p3 frags, compute mi 4-5
    ay0 = RDA(6,0); ay1 = RDA(6,1); ay2 = RDA(7,0); ay3 = RDA(7,1);
    MFMA16(4, ax0, ax1, ax2, ax3)
    // p3: compute mi 6-7
    MFMA16(6, ay0, ay1, ay2, ay3)

    #undef MFMA16
    #undef RDA

    // all reads of buf cur retired (consumed by MFMAs above); drain t+1's
    // staging (issued ~3000 cyc ago) and cross the tile boundary
    asm volatile("s_waitcnt vmcnt(0)" ::: "memory");
    asm volatile("s_barrier" ::: "memory");
  }

  #pragma unroll
  for (int mi = 0; mi < 8; ++mi)
    #pragma unroll
    for (int ni = 0; ni < 4; ++ni)
      #pragma unroll
      for (int j = 0; j < 4; ++j){
        const int row = m0 + wm * 128 + mi * 16 + fkc * 4 + j;
        const int col = n0 + wn * 64 + ni * 16 + fr;
        const float v = acc[mi][ni][j];
        if constexpr (OUT == 0){
          ((float*)C)[(size_t)z * (size_t)cbstr + (size_t)row * ldc + col] = v;
        } else {
          unsigned short* o = (unsigned short*)C;
          const unsigned short h = f2bf(v);
          o[(size_t)row * 2048 + col]        = h;
          o[(size_t)row * 2048 + 1024 + col] = f2bf(v - bf2f(h));
        }
      }
}

// W[e][n] f32 -> Wt[n][2048] = [Wt_h | Wt_l] bf16
__global__ __launch_bounds__(256)
void wtprep_kernel(const float* __restrict__ W, unsigned short* __restrict__ Wt)
{
  __shared__ float tile[64][65];
  const int e0 = blockIdx.x * 64, n0 = blockIdx.y * 64;
  const int t = threadIdx.x;
  const int r = t >> 2, cq = t & 3;
  #pragma unroll
  for (int i = 0; i < 4; ++i){
    float4 f = *(const float4*)(W + (size_t)(e0 + r) * 1024 + n0 + cq*16 + i*4);
    tile[r][cq*16 + i*4 + 0] = f.x;
    tile[r][cq*16 + i*4 + 1] = f.y;
    tile[r][cq*16 + i*4 + 2] = f.z;
    tile[r][cq*16 + i*4 + 3] = f.w;
  }
  __syncthreads();
  unsigned short h[16], l[16];
  #pragma unroll
  for (int i = 0; i < 16; ++i){
    float v = tile[cq*16 + i][r];
    h[i] = f2bf(v);
    l[i] = f2bf(v - bf2f(h[i]));
  }
  uint4 ha, hb, la4, lb4;
  ha.x=pack2(h[0],h[1]);   ha.y=pack2(h[2],h[3]);   ha.z=pack2(h[4],h[5]);   ha.w=pack2(h[6],h[7]);
  hb.x=pack2(h[8],h[9]);   hb.y=pack2(h[10],h[11]); hb.z=pack2(h[12],h[13]); hb.w=pack2(h[14],h[15]);
  la4.x=pack2(l[0],l[1]);  la4.y=pack2(l[2],l[3]);  la4.z=pack2(l[4],l[5]);  la4.w=pack2(l[6],l[7]);
  lb4.x=pack2(l[8],l[9]);  lb4.y=pack2(l[10],l[11]);lb4.z=pack2(l[12],l[13]);lb4.w=pack2(l[14],l[15]);
  size_t o = (size_t)(n0 + r) * 2048 + e0 + cq*16;
  *(uint4*)(Wt + o)          = ha;
  *(uint4*)(Wt + o + 8)      = hb;
  *(uint4*)(Wt + o + 1024)   = la4;
  *(uint4*)(Wt + o + 1032)   = lb4;
}

// q rows f32 [R][1024] -> qsplit[R][2048] = [q_h | q_l]
__global__ __launch_bounds__(256)
void qprep_kernel(const float* __restrict__ q, unsigned short* __restrict__ qs)
{
  const int gid = blockIdx.x * 256 + threadIdx.x;
  const int row = gid >> 7;
  const int c8  = (gid & 127) * 8;
  const float* src = q + (size_t)row * 1024 + c8;
  float4 f0 = *(const float4*)src;
  float4 f1 = *(const float4*)(src + 4);
  float vs[8] = {f0.x, f0.y, f0.z, f0.w, f1.x, f1.y, f1.z, f1.w};
  unsigned short h[8], l[8];
  #pragma unroll
  for (int i = 0; i < 8; ++i){ h[i] = f2bf(vs[i]); l[i] = f2bf(vs[i] - bf2f(h[i])); }
  uint4 hv, lv;
  hv.x=pack2(h[0],h[1]); hv.y=pack2(h[2],h[3]); hv.z=pack2(h[4],h[5]); hv.w=pack2(h[6],h[7]);
  lv.x=pack2(l[0],l[1]); lv.y=pack2(l[2],l[3]); lv.z=pack2(l[4],l[5]); lv.w=pack2(l[6],l[7]);
  size_t o = (size_t)row * 2048 + c8;
  *(uint4*)(qs + o)        = hv;
  *(uint4*)(qs + o + 1024) = lv;
}

// k[b][kv][e] f32 -> ksplit[b][kv][2048] = [k_h | k_l] and kT[b][e][kv] (hi)
__global__ __launch_bounds__(256)
void kprep_kernel(const float* __restrict__ kin, unsigned short* __restrict__ ks,
                  unsigned short* __restrict__ kT)
{
  __shared__ float tile[64][65];
  const int bz = blockIdx.z;
  const float* kb = kin + (size_t)bz * 2048 * 1024;
  unsigned short* ksb = ks + (size_t)bz * 2048 * 2048;
  unsigned short* kTb = kT + (size_t)bz * 1024 * 2048;
  const int kv0 = blockIdx.x * 64, e0 = blockIdx.y * 64;
  const int t = threadIdx.x;
  const int r = t >> 2, cq = t & 3;
  #pragma unroll
  for (int i = 0; i < 4; ++i){
    float4 f = *(const float4*)(kb + (size_t)(kv0 + r) * 1024 + e0 + cq*16 + i*4);
    unsigned short h0=f2bf(f.x), h1=f2bf(f.y), h2=f2bf(f.z), h3=f2bf(f.w);
    uint2 hv, lv;
    hv.x = pack2(h0, h1); hv.y = pack2(h2, h3);
    lv.x = pack2(f2bf(f.x - bf2f(h0)), f2bf(f.y - bf2f(h1)));
    lv.y = pack2(f2bf(f.z - bf2f(h2)), f2bf(f.w - bf2f(h3)));
    size_t o = (size_t)(kv0 + r) * 2048 + e0 + cq*16 + i*4;
    *(uint2*)(ksb + o)        = hv;
    *(uint2*)(ksb + o + 1024) = lv;
    tile[r][cq*16 + i*4 + 0] = f.x;
    tile[r][cq*16 + i*4 + 1] = f.y;
    tile[r][cq*16 + i*4 + 2] = f.z;
    tile[r][cq*16 + i*4 + 3] = f.w;
  }
  __syncthreads();
  unsigned short h[16];
  #pragma unroll
  for (int i = 0; i < 16; ++i) h[i] = f2bf(tile[cq*16 + i][r]);
  uint4 va, vb;
  va.x=pack2(h[0],h[1]);  va.y=pack2(h[2],h[3]);   va.z=pack2(h[4],h[5]);   va.w=pack2(h[6],h[7]);
  vb.x=pack2(h[8],h[9]);  vb.y=pack2(h[10],h[11]); vb.z=pack2(h[12],h[13]); vb.w=pack2(h[14],h[15]);
  size_t o = (size_t)(e0 + r) * 2048 + kv0 + cq*16;
  *(uint4*)(kTb + o)     = va;
  *(uint4*)(kTb + o + 8) = vb;
}

// exact row softmax over 2048 f32, then * mask, -> bf16
__global__ __launch_bounds__(256)
void softmax_kernel(const float* __restrict__ S, const int* __restrict__ mask,
                    unsigned short* __restrict__ P)
{
  const int row = blockIdx.x;
  const float* s = S + (size_t)row * 2048;
  const int* mk = mask + (size_t)row * 2048;
  unsigned short* p = P + (size_t)row * 2048;
  const int t = threadIdx.x;
  float4 v0 = ((const float4*)s)[t];
  float4 v1 = ((const float4*)s)[t + 256];
  float m = fmaxf(fmaxf(fmaxf(v0.x, v0.y), fmaxf(v0.z, v0.w)),
                  fmaxf(fmaxf(v1.x, v1.y), fmaxf(v1.z, v1.w)));
  #pragma unroll
  for (int off = 32; off > 0; off >>= 1) m = fmaxf(m, __shfl_xor(m, off));
  __shared__ float rmax[4], rsum[4];
  const int wid = t >> 6;
  if ((t & 63) == 0) rmax[wid] = m;
  __syncthreads();
  m = fmaxf(fmaxf(rmax[0], rmax[1]), fmaxf(rmax[2], rmax[3]));
  float e0 = __expf(v0.x - m), e1 = __expf(v0.y - m), e2 = __expf(v0.z - m), e3 = __expf(v0.w - m);
  float e4 = __expf(v1.x - m), e5 = __expf(v1.y - m), e6 = __expf(v1.z - m), e7 = __expf(v1.w - m);
  float ssum = ((e0 + e1) + (e2 + e3)) + ((e4 + e5) + (e6 + e7));
  #pragma unroll
  for (int off = 32; off > 0; off >>= 1) ssum += __shfl_xor(ssum, off);
  if ((t & 63) == 0) rsum[wid] = ssum;
  __syncthreads();
  float inv = 1.f / (rsum[0] + rsum[1] + rsum[2] + rsum[3]);
  int4 m0 = ((const int4*)mk)[t];
  int4 m1 = ((const int4*)mk)[t + 256];
  ushort4 o0, o1;
  o0.x = f2bf(e0 * inv * (float)m0.x);
  o0.y = f2bf(e1 * inv * (float)m0.y);
  o0.z = f2bf(e2 * inv * (float)m0.z);
  o0.w = f2bf(e3 * inv * (float)m0.w);
  o1.x = f2bf(e4 * inv * (float)m1.x);
  o1.y = f2bf(e5 * inv * (float)m1.y);
  o1.z = f2bf(e6 * inv * (float)m1.z);
  o1.w = f2bf(e7 * inv * (float)m1.w);
  ((ushort4*)p)[t]       = o0;
  ((ushort4*)p)[t + 256] = o1;
}

extern "C" void kernel_launch(void* const* d_in, const int* in_sizes, int n_in,
                              void* d_out, int out_size, void* d_ws, size_t ws_size,
                              hipStream_t stream)
{
  (void)in_sizes; (void)n_in; (void)out_size;
  const float* kin  = (const float*)d_in[0];
  const float* qin  = (const float*)d_in[1];
  const float* Win  = (const float*)d_in[2];
  const int*   mask = (const int*)d_in[3];

  // ws: Wt (4MB) | per-batch { qsplit 8 | qwsplit 8 | ksplit 8 | kT 4 | S 16 | P 8 } = 52MB
  int bpc = 1;
  {
    const size_t per_b = (size_t)2048*2048*2*3 + (size_t)1024*2048*2
                       + (size_t)2048*2048*4 + (size_t)2048*2048*2;
    const size_t fixed = (size_t)1024*2048*2;
    const int cands[5] = {16, 8, 4, 2, 1};
    for (int i = 0; i < 5; ++i){
      if (fixed + (size_t)cands[i] * per_b <= ws_size){ bpc = cands[i]; break; }
    }
  }
  unsigned short* Wt      = (unsigned short*)d_ws;
  unsigned short* qsplit  = Wt + (size_t)1024*2048;
  unsigned short* qwsplit = qsplit  + (size_t)bpc*2048*2048;
  unsigned short* ksplit  = qwsplit + (size_t)bpc*2048*2048;
  unsigned short* kT      = ksplit  + (size_t)bpc*2048*2048;
  float*          Sb      = (float*)(kT + (size_t)bpc*1024*2048);
  unsigned short* Pb      = (unsigned short*)(Sb + (size_t)bpc*2048*2048);

  wtprep_kernel<<<dim3(16, 16, 1), 256, 0, stream>>>(Win, Wt);

  for (int cb = 0; cb < 16; cb += bpc){
    qprep_kernel<<<dim3(bpc * 1024, 1, 1), 256, 0, stream>>>(
        qin + (size_t)cb * 2048 * 1024, qsplit);

    // K1: qw = q @ W  (3-pass split via remap, NT=48) -> qwsplit [h|l]
    gemm256<1, 1><<<dim3(bpc * 8, 4, 1), 512, 0, stream>>>(
        qsplit, Wt, qwsplit, 48, 2048, 2048, 0, 0, 0, 0);

    kprep_kernel<<<dim3(32, 16, bpc), 256, 0, stream>>>(
        kin + (size_t)cb * 2048 * 1024, ksplit, kT);

    // K2: S = qw @ k^T (3-pass split via remap, NT=48), batched
    gemm256<1, 0><<<dim3(8, 8, bpc), 512, 0, stream>>>(
        qwsplit, ksplit, Sb, 48, 2048, 2048, 2048,
        (long)2048 * 2048, (long)2048 * 2048, (long)2048 * 2048);

    // K3: row softmax * mask -> P (bf16)
    softmax_kernel<<<dim3(bpc * 2048, 1, 1), 256, 0, stream>>>(
        Sb, mask + (size_t)cb * 2048 * 2048, Pb);

    // K4: O = P @ kT^T (plain, NT=32), batched -> d_out
    gemm256<0, 0><<<dim3(8, 4, bpc), 512, 0, stream>>>(
        Pb, kT, (float*)d_out + (size_t)cb * 2048 * 1024, 32, 2048, 2048, 1024,
        (long)2048 * 2048, (long)1024 * 2048, (long)2048 * 1024);
  }
}

// Round 11
// 923.792 us; speedup vs baseline: 1.2501x; 1.2501x over previous
//
#include <hip/hip_runtime.h>
#include <stdint.h>

typedef short bfrag __attribute__((ext_vector_type(8)));   // 8 bf16 (4 VGPR)
typedef float facc4 __attribute__((ext_vector_type(4)));   // MFMA accumulator

__device__ __forceinline__ unsigned short f2bf(float x){
  union { float f; uint32_t u; } v; v.f = x;
  uint32_t r = v.u + 0x7FFFu + ((v.u >> 16) & 1u);   // RNE
  return (unsigned short)(r >> 16);
}
__device__ __forceinline__ float bf2f(unsigned short h){
  union { uint32_t u; float f; } v; v.u = ((uint32_t)h) << 16; return v.f;
}
__device__ __forceinline__ uint32_t pack2(unsigned short a, unsigned short b){
  return (uint32_t)a | ((uint32_t)b << 16);
}

__device__ __forceinline__ void gload_lds16(const void* g, void* l){
  __builtin_amdgcn_global_load_lds(
      (const __attribute__((address_space(1))) void*)g,
      (__attribute__((address_space(3))) void*)l, 16, 0, 0);
}

// ---------------------------------------------------------------------------
// 256x256 8-phase bf16 GEMM, 8 waves (2M x 4N), BK=64, 128 KB LDS dbuf.
// == r9 schedule (best: 450us K2) with COALESCED STAGING ==
//
// LDS block layout: tile = 32 blocks of 1KB; block b covers rows b*8..+7,
// full BK=64.  Within a block, row r's 16B slot s holds global k-chunk
// (s ^ r)  [XOR involution, same on DMA-source and ds_read -- rule #21].
//   - gload (1KB): lane l = r*8+s reads global row (b*8+r), chunk (s^r)
//     -> 8 rows x full 128B aligned line each, fully consumed (ideal
//     coalescing; r9 had 16 rows x 64B half-lines).
//   - ds_read frag(rg,ks): lane(fr,fkc) reads block rg*2+(fr>>3),
//     row fr&7, slot ((ks*4+fkc)^(fr&7)) -> per-16-lane phase all 8
//     bank-quads hit by 2 lanes = 2-way = free (m136).
//
// Schedule per tile t (4 phases, 2 barriers each), staging 1/3/3/1:
//   p0: stage A G3(t+1->buf^1); p1: B j0,j1 + A G0 (t+2->cur);
//   p2: B j2,j3 + A G1; p3: A G2.   Gate at p3: vmcnt(7) leaves exactly
//   t+2's 7 in flight (never 0 -- T4).  p0: lgkmcnt(8) stagger.
//   After each pre-MFMA barrier: explicit lgkmcnt(0)+sched_barrier(0)
//   (m201 semantics), setprio(1), 16 MFMA ks-major, setprio(0).
//
// A block group G_p = {4p..4p+3, 16+4p..16+4p+3} (consumed by MFMA phase p).
// REMAP=1: A,B are [hi|lo], NT=48 encodes Ah*Bh+Ah*Bl+Al*Bh via
// akt=(kt<16?kt:kt-16), bkt=(kt<32?kt:kt-32). REMAP=0: plain, NT=K/64.
// OUT: 0 = f32 C. 1 = split write hi at [row*2048+col], lo at +1024.
// T1: bijective XCD swizzle (m204) on flattened block id.
// ---------------------------------------------------------------------------
template<int REMAP, int OUT>
__global__ __launch_bounds__(512, 1)
void gemm256(const unsigned short* __restrict__ A,
             const unsigned short* __restrict__ B,
             void* __restrict__ C,
             int NT, int lda, int ldb, int ldc,
             long abstr, long bbstr, long cbstr)
{
  __shared__ __align__(16) unsigned short lds[2][2][16384];   // 128 KB

  const int tid  = threadIdx.x;
  const int lane = tid & 63;
  const int wv   = tid >> 6;          // 0..7
  const int wm   = wv >> 2;           // 0..1  -> 128 rows
  const int wn   = wv & 3;            // 0..3  -> 64 cols

  // T1: bijective XCD-aware remap of the flattened block id (m204)
  const int gx = gridDim.x, gy = gridDim.y;
  const int nwg  = gx * gy * (int)gridDim.z;
  const int orig = blockIdx.x + gx * (blockIdx.y + gy * blockIdx.z);
  const int qd = nwg >> 3, rm = nwg & 7;
  const int xcd = orig & 7, idx = orig >> 3;
  const int swz = (xcd < rm ? xcd * (qd + 1) : rm * (qd + 1) + (xcd - rm) * qd) + idx;
  const int m0 = (swz % gx) * 256;
  const int rest = swz / gx;
  const int n0 = (rest % gy) * 256;
  const int z  = rest / gy;

  const unsigned short* Ab = A + (size_t)z * (size_t)abstr;
  const unsigned short* Bb = B + (size_t)z * (size_t)bbstr;

  const int fr  = lane & 15;
  const int fkc = lane >> 4;          // 0..3
  // ds_read per-thread offsets (shorts): block sel + row + swizzled slot
  const int rlow = fr & 7, rhi = fr >> 3;
  const int aoff0 = rhi * 512 + rlow * 64 + ((fkc ^ rlow)) * 8;        // ks=0
  const int aoff1 = rhi * 512 + rlow * 64 + (((4 | fkc) ^ rlow)) * 8;  // ks=1
  // staging per-thread: row-in-block + swizzled source chunk
  const int r8 = lane >> 3, s8 = lane & 7;
  const int cswz = (s8 ^ r8) * 8;     // element offset within 128B row-slice

  // stage one A block of group G_p (8 blocks, one per wave)
  auto stageA1 = [&](int buf, int kt, int p){
    int akt = kt; if (REMAP) akt = (kt < 16) ? kt : kt - 16;
    const int ab = 4 * p + (wv & 3) + ((wv >> 2) << 4);
    gload_lds16(Ab + (size_t)(m0 + ab * 8 + r8) * lda + akt * 64 + cswz,
                &lds[buf][0][ab * 512]);
  };
  // stage one quarter of B (8 blocks, one per wave); j = 0..3 covers all 32
  auto stageB = [&](int buf, int kt, int j){
    int bkt = kt; if (REMAP) bkt = (kt < 32) ? kt : kt - 32;
    const int bb = j * 8 + wv;
    gload_lds16(Bb + (size_t)(n0 + bb * 8 + r8) * ldb + bkt * 64 + cswz,
                &lds[buf][1][bb * 512]);
  };

  facc4 acc[8][4];
  #pragma unroll
  for (int a = 0; a < 8; ++a)
    #pragma unroll
    for (int b = 0; b < 4; ++b)
      acc[a][b] = (facc4){0.f, 0.f, 0.f, 0.f};

  // prologue: tile0 fully (8/wave), tile1 all but G3 (7/wave) -> 15 in flight
  #pragma unroll
  for (int j = 0; j < 4; ++j) stageB(0, 0, j);
  stageA1(0, 0, 0); stageA1(0, 0, 1); stageA1(0, 0, 2); stageA1(0, 0, 3);
  if (NT > 1){
    #pragma unroll
    for (int j = 0; j < 4; ++j) stageB(1, 1, j);
    stageA1(1, 1, 0); stageA1(1, 1, 1); stageA1(1, 1, 2);
    asm volatile("s_waitcnt vmcnt(7)" ::: "memory");    // tile0's 8 landed
  } else {
    asm volatile("s_waitcnt vmcnt(0)" ::: "memory");
  }
  asm volatile("s_barrier" ::: "memory");

  for (int t = 0; t < NT; ++t){
    const int cur = t & 1;
    const unsigned short* la = lds[cur][0];
    const unsigned short* lb = lds[cur][1];
    bfrag bv[4][2];
    #pragma unroll
    for (int p = 0; p < 4; ++p){
      const int mi0 = 2 * p, mi1 = 2 * p + 1;
      // --- ds_read this phase's fragments ---
      bfrag a00 = *(const bfrag*)(la + (wm * 8 + mi0) * 1024 + aoff0);
      bfrag a01 = *(const bfrag*)(la + (wm * 8 + mi0) * 1024 + aoff1);
      bfrag a10 = *(const bfrag*)(la + (wm * 8 + mi1) * 1024 + aoff0);
      bfrag a11 = *(const bfrag*)(la + (wm * 8 + mi1) * 1024 + aoff1);
      if (p == 0){
        #pragma unroll
        for (int ni = 0; ni < 4; ++ni){
          bv[ni][0] = *(const bfrag*)(lb + (wn * 4 + ni) * 1024 + aoff0);
          bv[ni][1] = *(const bfrag*)(lb + (wn * 4 + ni) * 1024 + aoff1);
        }
      }
      // --- stage issue (death-region-safe, 1/3/3/1) ---
      if (p == 0 && t + 1 < NT) stageA1(cur ^ 1, t + 1, 3);
      if (p == 1 && t + 2 < NT){ stageB(cur, t + 2, 0); stageB(cur, t + 2, 1); stageA1(cur, t + 2, 0); }
      if (p == 2 && t + 2 < NT){ stageB(cur, t + 2, 2); stageB(cur, t + 2, 3); stageA1(cur, t + 2, 1); }
      if (p == 3 && t + 2 < NT) stageA1(cur, t + 2, 2);

      if (p == 0) asm volatile("s_waitcnt lgkmcnt(8)" ::: "memory");
      asm volatile("s_barrier" ::: "memory");
      asm volatile("s_waitcnt lgkmcnt(0)" ::: "memory");
      __builtin_amdgcn_sched_barrier(0);

      __builtin_amdgcn_s_setprio(1);
      // ks-major: 8 independent MFMAs, then 8 each depending on one 8 back
      #pragma unroll
      for (int ni = 0; ni < 4; ++ni){
        acc[mi0][ni] = __builtin_amdgcn_mfma_f32_16x16x32_bf16(a00, bv[ni][0], acc[mi0][ni], 0, 0, 0);
        acc[mi1][ni] = __builtin_amdgcn_mfma_f32_16x16x32_bf16(a10, bv[ni][0], acc[mi1][ni], 0, 0, 0);
      }
      #pragma unroll
      for (int ni = 0; ni < 4; ++ni){
        acc[mi0][ni] = __builtin_amdgcn_mfma_f32_16x16x32_bf16(a01, bv[ni][1], acc[mi0][ni], 0, 0, 0);
        acc[mi1][ni] = __builtin_amdgcn_mfma_f32_16x16x32_bf16(a11, bv[ni][1], acc[mi1][ni], 0, 0, 0);
      }
      __builtin_amdgcn_s_setprio(0);

      if (p == 3 && t + 1 < NT){
        if (t + 2 < NT) asm volatile("s_waitcnt vmcnt(7)" ::: "memory");
        else            asm volatile("s_waitcnt vmcnt(0)" ::: "memory");
      }
      asm volatile("s_barrier" ::: "memory");
    }
  }

  #pragma unroll
  for (int mi = 0; mi < 8; ++mi)
    #pragma unroll
    for (int ni = 0; ni < 4; ++ni)
      #pragma unroll
      for (int j = 0; j < 4; ++j){
        const int row = m0 + wm * 128 + mi * 16 + fkc * 4 + j;
        const int col = n0 + wn * 64 + ni * 16 + fr;
        const float v = acc[mi][ni][j];
        if constexpr (OUT == 0){
          ((float*)C)[(size_t)z * (size_t)cbstr + (size_t)row * ldc + col] = v;
        } else {
          unsigned short* o = (unsigned short*)C;
          const unsigned short h = f2bf(v);
          o[(size_t)row * 2048 + col]        = h;
          o[(size_t)row * 2048 + 1024 + col] = f2bf(v - bf2f(h));
        }
      }
}

// W[e][n] f32 -> Wt[n][2048] = [Wt_h | Wt_l] bf16
__global__ __launch_bounds__(256)
void wtprep_kernel(const float* __restrict__ W, unsigned short* __restrict__ Wt)
{
  __shared__ float tile[64][65];
  const int e0 = blockIdx.x * 64, n0 = blockIdx.y * 64;
  const int t = threadIdx.x;
  const int r = t >> 2, cq = t & 3;
  #pragma unroll
  for (int i = 0; i < 4; ++i){
    float4 f = *(const float4*)(W + (size_t)(e0 + r) * 1024 + n0 + cq*16 + i*4);
    tile[r][cq*16 + i*4 + 0] = f.x;
    tile[r][cq*16 + i*4 + 1] = f.y;
    tile[r][cq*16 + i*4 + 2] = f.z;
    tile[r][cq*16 + i*4 + 3] = f.w;
  }
  __syncthreads();
  unsigned short h[16], l[16];
  #pragma unroll
  for (int i = 0; i < 16; ++i){
    float v = tile[cq*16 + i][r];
    h[i] = f2bf(v);
    l[i] = f2bf(v - bf2f(h[i]));
  }
  uint4 ha, hb, la4, lb4;
  ha.x=pack2(h[0],h[1]);   ha.y=pack2(h[2],h[3]);   ha.z=pack2(h[4],h[5]);   ha.w=pack2(h[6],h[7]);
  hb.x=pack2(h[8],h[9]);   hb.y=pack2(h[10],h[11]); hb.z=pack2(h[12],h[13]); hb.w=pack2(h[14],h[15]);
  la4.x=pack2(l[0],l[1]);  la4.y=pack2(l[2],l[3]);  la4.z=pack2(l[4],l[5]);  la4.w=pack2(l[6],l[7]);
  lb4.x=pack2(l[8],l[9]);  lb4.y=pack2(l[10],l[11]);lb4.z=pack2(l[12],l[13]);lb4.w=pack2(l[14],l[15]);
  size_t o = (size_t)(n0 + r) * 2048 + e0 + cq*16;
  *(uint4*)(Wt + o)          = ha;
  *(uint4*)(Wt + o + 8)      = hb;
  *(uint4*)(Wt + o + 1024)   = la4;
  *(uint4*)(Wt + o + 1032)   = lb4;
}

// q rows f32 [R][1024] -> qsplit[R][2048] = [q_h | q_l]
__global__ __launch_bounds__(256)
void qprep_kernel(const float* __restrict__ q, unsigned short* __restrict__ qs)
{
  const int gid = blockIdx.x * 256 + threadIdx.x;
  const int row = gid >> 7;
  const int c8  = (gid & 127) * 8;
  const float* src = q + (size_t)row * 1024 + c8;
  float4 f0 = *(const float4*)src;
  float4 f1 = *(const float4*)(src + 4);
  float vs[8] = {f0.x, f0.y, f0.z, f0.w, f1.x, f1.y, f1.z, f1.w};
  unsigned short h[8], l[8];
  #pragma unroll
  for (int i = 0; i < 8; ++i){ h[i] = f2bf(vs[i]); l[i] = f2bf(vs[i] - bf2f(h[i])); }
  uint4 hv, lv;
  hv.x=pack2(h[0],h[1]); hv.y=pack2(h[2],h[3]); hv.z=pack2(h[4],h[5]); hv.w=pack2(h[6],h[7]);
  lv.x=pack2(l[0],l[1]); lv.y=pack2(l[2],l[3]); lv.z=pack2(l[4],l[5]); lv.w=pack2(l[6],l[7]);
  size_t o = (size_t)row * 2048 + c8;
  *(uint4*)(qs + o)        = hv;
  *(uint4*)(qs + o + 1024) = lv;
}

// k[b][kv][e] f32 -> ksplit[b][kv][2048] = [k_h | k_l] and kT[b][e][kv] (hi)
__global__ __launch_bounds__(256)
void kprep_kernel(const float* __restrict__ kin, unsigned short* __restrict__ ks,
                  unsigned short* __restrict__ kT)
{
  __shared__ float tile[64][65];
  const int bz = blockIdx.z;
  const float* kb = kin + (size_t)bz * 2048 * 1024;
  unsigned short* ksb = ks + (size_t)bz * 2048 * 2048;
  unsigned short* kTb = kT + (size_t)bz * 1024 * 2048;
  const int kv0 = blockIdx.x * 64, e0 = blockIdx.y * 64;
  const int t = threadIdx.x;
  const int r = t >> 2, cq = t & 3;
  #pragma unroll
  for (int i = 0; i < 4; ++i){
    float4 f = *(const float4*)(kb + (size_t)(kv0 + r) * 1024 + e0 + cq*16 + i*4);
    unsigned short h0=f2bf(f.x), h1=f2bf(f.y), h2=f2bf(f.z), h3=f2bf(f.w);
    uint2 hv, lv;
    hv.x = pack2(h0, h1); hv.y = pack2(h2, h3);
    lv.x = pack2(f2bf(f.x - bf2f(h0)), f2bf(f.y - bf2f(h1)));
    lv.y = pack2(f2bf(f.z - bf2f(h2)), f2bf(f.w - bf2f(h3)));
    size_t o = (size_t)(kv0 + r) * 2048 + e0 + cq*16 + i*4;
    *(uint2*)(ksb + o)        = hv;
    *(uint2*)(ksb + o + 1024) = lv;
    tile[r][cq*16 + i*4 + 0] = f.x;
    tile[r][cq*16 + i*4 + 1] = f.y;
    tile[r][cq*16 + i*4 + 2] = f.z;
    tile[r][cq*16 + i*4 + 3] = f.w;
  }
  __syncthreads();
  unsigned short h[16];
  #pragma unroll
  for (int i = 0; i < 16; ++i) h[i] = f2bf(tile[cq*16 + i][r]);
  uint4 va, vb;
  va.x=pack2(h[0],h[1]);  va.y=pack2(h[2],h[3]);   va.z=pack2(h[4],h[5]);   va.w=pack2(h[6],h[7]);
  vb.x=pack2(h[8],h[9]);  vb.y=pack2(h[10],h[11]); vb.z=pack2(h[12],h[13]); vb.w=pack2(h[14],h[15]);
  size_t o = (size_t)(e0 + r) * 2048 + kv0 + cq*16;
  *(uint4*)(kTb + o)     = va;
  *(uint4*)(kTb + o + 8) = vb;
}

// exact row softmax over 2048 f32, then * mask, -> bf16
__global__ __launch_bounds__(256)
void softmax_kernel(const float* __restrict__ S, const int* __restrict__ mask,
                    unsigned short* __restrict__ P)
{
  const int row = blockIdx.x;
  const float* s = S + (size_t)row * 2048;
  const int* mk = mask + (size_t)row * 2048;
  unsigned short* p = P + (size_t)row * 2048;
  const int t = threadIdx.x;
  float4 v0 = ((const float4*)s)[t];
  float4 v1 = ((const float4*)s)[t + 256];
  float m = fmaxf(fmaxf(fmaxf(v0.x, v0.y), fmaxf(v0.z, v0.w)),
                  fmaxf(fmaxf(v1.x, v1.y), fmaxf(v1.z, v1.w)));
  #pragma unroll
  for (int off = 32; off > 0; off >>= 1) m = fmaxf(m, __shfl_xor(m, off));
  __shared__ float rmax[4], rsum[4];
  const int wid = t >> 6;
  if ((t & 63) == 0) rmax[wid] = m;
  __syncthreads();
  m = fmaxf(fmaxf(rmax[0], rmax[1]), fmaxf(rmax[2], rmax[3]));
  float e0 = __expf(v0.x - m), e1 = __expf(v0.y - m), e2 = __expf(v0.z - m), e3 = __expf(v0.w - m);
  float e4 = __expf(v1.x - m), e5 = __expf(v1.y - m), e6 = __expf(v1.z - m), e7 = __expf(v1.w - m);
  float ssum = ((e0 + e1) + (e2 + e3)) + ((e4 + e5) + (e6 + e7));
  #pragma unroll
  for (int off = 32; off > 0; off >>= 1) ssum += __shfl_xor(ssum, off);
  if ((t & 63) == 0) rsum[wid] = ssum;
  __syncthreads();
  float inv = 1.f / (rsum[0] + rsum[1] + rsum[2] + rsum[3]);
  int4 m0 = ((const int4*)mk)[t];
  int4 m1 = ((const int4*)mk)[t + 256];
  ushort4 o0, o1;
  o0.x = f2bf(e0 * inv * (float)m0.x);
  o0.y = f2bf(e1 * inv * (float)m0.y);
  o0.z = f2bf(e2 * inv * (float)m0.z);
  o0.w = f2bf(e3 * inv * (float)m0.w);
  o1.x = f2bf(e4 * inv * (float)m1.x);
  o1.y = f2bf(e5 * inv * (float)m1.y);
  o1.z = f2bf(e6 * inv * (float)m1.z);
  o1.w = f2bf(e7 * inv * (float)m1.w);
  ((ushort4*)p)[t]       = o0;
  ((ushort4*)p)[t + 256] = o1;
}

extern "C" void kernel_launch(void* const* d_in, const int* in_sizes, int n_in,
                              void* d_out, int out_size, void* d_ws, size_t ws_size,
                              hipStream_t stream)
{
  (void)in_sizes; (void)n_in; (void)out_size;
  const float* kin  = (const float*)d_in[0];
  const float* qin  = (const float*)d_in[1];
  const float* Win  = (const float*)d_in[2];
  const int*   mask = (const int*)d_in[3];

  // ws: Wt (4MB) | per-batch { qsplit 8 | qwsplit 8 | ksplit 8 | kT 4 | S 16 | P 8 } = 52MB
  int bpc = 1;
  {
    const size_t per_b = (size_t)2048*2048*2*3 + (size_t)1024*2048*2
                       + (size_t)2048*2048*4 + (size_t)2048*2048*2;
    const size_t fixed = (size_t)1024*2048*2;
    const int cands[5] = {16, 8, 4, 2, 1};
    for (int i = 0; i < 5; ++i){
      if (fixed + (size_t)cands[i] * per_b <= ws_size){ bpc = cands[i]; break; }
    }
  }
  unsigned short* Wt      = (unsigned short*)d_ws;
  unsigned short* qsplit  = Wt + (size_t)1024*2048;
  unsigned short* qwsplit = qsplit  + (size_t)bpc*2048*2048;
  unsigned short* ksplit  = qwsplit + (size_t)bpc*2048*2048;
  unsigned short* kT      = ksplit  + (size_t)bpc*2048*2048;
  float*          Sb      = (float*)(kT + (size_t)bpc*1024*2048);
  unsigned short* Pb      = (unsigned short*)(Sb + (size_t)bpc*2048*2048);

  wtprep_kernel<<<dim3(16, 16, 1), 256, 0, stream>>>(Win, Wt);

  for (int cb = 0; cb < 16; cb += bpc){
    qprep_kernel<<<dim3(bpc * 1024, 1, 1), 256, 0, stream>>>(
        qin + (size_t)cb * 2048 * 1024, qsplit);

    // K1: qw = q @ W  (3-pass split via remap, NT=48) -> qwsplit [h|l]
    gemm256<1, 1><<<dim3(bpc * 8, 4, 1), 512, 0, stream>>>(
        qsplit, Wt, qwsplit, 48, 2048, 2048, 0, 0, 0, 0);

    kprep_kernel<<<dim3(32, 16, bpc), 256, 0, stream>>>(
        kin + (size_t)cb * 2048 * 1024, ksplit, kT);

    // K2: S = qw @ k^T (3-pass split via remap, NT=48), batched
    gemm256<1, 0><<<dim3(8, 8, bpc), 512, 0, stream>>>(
        qwsplit, ksplit, Sb, 48, 2048, 2048, 2048,
        (long)2048 * 2048, (long)2048 * 2048, (long)2048 * 2048);

    // K3: row softmax * mask -> P (bf16)
    softmax_kernel<<<dim3(bpc * 2048, 1, 1), 256, 0, stream>>>(
        Sb, mask + (size_t)cb * 2048 * 2048, Pb);

    // K4: O = P @ kT^T (plain, NT=32), batched -> d_out
    gemm256<0, 0><<<dim3(8, 4, bpc), 512, 0, stream>>>(
        Pb, kT, (float*)d_out + (size_t)cb * 2048 * 1024, 32, 2048, 2048, 1024,
        (long)2048 * 2048, (long)1024 * 2048, (long)2048 * 1024);
  }
}